// Round 7
// baseline (387.256 us; speedup 1.0000x reference)
//
#include <hip/hip_runtime.h>
#include <hip/hip_bf16.h>

#define T_SEQ 4096
#define HIDDEN 2560
#define NH 8
#define NKV 4
#define HD 256
#define WINDOW 1024
#define SM_SCALE 0.0625f

typedef __bf16 bf16x8 __attribute__((ext_vector_type(8)));
typedef float f32x4 __attribute__((ext_vector_type(4)));
typedef __hip_bfloat16 bf16;

#define GLOAD_LDS(g, l) \
  __builtin_amdgcn_global_load_lds((const __attribute__((address_space(1))) void*)(g), \
                                   (__attribute__((address_space(3))) void*)(l), 16, 0, 0)

// ---------- fused prep: x fp32->bf16 + all 4 weight transposes (1 launch) ----------
__global__ __launch_bounds__(256) void k_prep(
    const float* __restrict__ x,
    const float* __restrict__ Wq, const float* __restrict__ Wk,
    const float* __restrict__ Wv, const float* __restrict__ Wo,
    bf16* __restrict__ x_b, bf16* __restrict__ Wqkv_t, bf16* __restrict__ Wo_t)
{
  __shared__ bf16 t[64 * 72];  // +8 pad breaks bank conflicts on transposed read
  const int tid = threadIdx.x;
  const int b = blockIdx.x;
  if (b < 5120) {
    const size_t i = (size_t)b * 256 + tid;
    const float4 a = ((const float4*)x)[i * 2];
    const float4 c = ((const float4*)x)[i * 2 + 1];
    bf16 tmp[8];
    tmp[0] = __float2bfloat16(a.x); tmp[1] = __float2bfloat16(a.y);
    tmp[2] = __float2bfloat16(a.z); tmp[3] = __float2bfloat16(a.w);
    tmp[4] = __float2bfloat16(c.x); tmp[5] = __float2bfloat16(c.y);
    tmp[6] = __float2bfloat16(c.z); tmp[7] = __float2bfloat16(c.w);
    *(bf16x8*)(x_b + i * 8) = *(bf16x8*)tmp;
    return;
  }
  int b2 = b - 5120;
  const float* src; bf16* dst; int srs, drs, nx;
  if (b2 < 1280)      { src = Wq; dst = Wqkv_t;                        srs = 2048; drs = 2560; nx = 32; }
  else if (b2 < 1920) { b2 -= 1280; src = Wk; dst = Wqkv_t + (size_t)2048 * 2560; srs = 1024; drs = 2560; nx = 16; }
  else if (b2 < 2560) { b2 -= 1920; src = Wv; dst = Wqkv_t + (size_t)3072 * 2560; srs = 1024; drs = 2560; nx = 16; }
  else                { b2 -= 2560; src = Wo; dst = Wo_t;              srs = 2560; drs = 2048; nx = 40; }
  const int c0 = (b2 % nx) * 64;
  const int r0 = (b2 / nx) * 64;
  const int rr = tid >> 3;
  const int cc = (tid & 7) * 8;
#pragma unroll
  for (int p = 0; p < 2; ++p) {
    const float* sp = src + (size_t)(r0 + p * 32 + rr) * srs + c0 + cc;
    const float4 a = *(const float4*)sp;
    const float4 c = *(const float4*)(sp + 4);
    bf16* tp = &t[(p * 32 + rr) * 72 + cc];
    tp[0] = __float2bfloat16(a.x); tp[1] = __float2bfloat16(a.y);
    tp[2] = __float2bfloat16(a.z); tp[3] = __float2bfloat16(a.w);
    tp[4] = __float2bfloat16(c.x); tp[5] = __float2bfloat16(c.y);
    tp[6] = __float2bfloat16(c.z); tp[7] = __float2bfloat16(c.w);
  }
  __syncthreads();
#pragma unroll
  for (int p = 0; p < 2; ++p) {
    const int n = p * 32 + rr;
    bf16x8 v;
#pragma unroll
    for (int i = 0; i < 8; ++i) v[i] = ((const __bf16*)t)[(cc + i) * 72 + n];
    *(bf16x8*)(dst + (size_t)(c0 + n) * drs + r0 + cc) = v;
  }
}

// ---------- 256x256-tile bf16 GEMM, software-pipelined 4-phase ----------
// R7: every fragment set is ds_read 1-2 phases BEFORE its MFMA uses it, so the
// LDS drain overlaps the current phase's MFMA cluster (R4-R6 read-then-use in
// the same phase serialized LDS (~2260cyc) + MFMA (~2483cyc) per K-tile).
// Quadrant order P1..P4 = (a_lo,b_lo),(a_lo,b_hi),(a_hi,b_hi),(a_hi,b_lo):
// each register set's two uses are consecutive, freeing it for the next tile's
// pre-read. 2-K-tile unroll -> compile-time buffers. Counted vmcnt placed
// BEFORE a barrier that precedes the cross-wave reads it guards (per-wave
// vmcnt + s_barrier = block-wide visibility). Stages: B(t+1)@P1/P2, A(t+2)@P3/P4.
template <typename OutT>
__global__ __launch_bounds__(512, 2) void k_gemm8(
    const bf16* __restrict__ A, const bf16* __restrict__ Bt,
    OutT* __restrict__ C, int M, int N, int K)
{
  __shared__ bf16 As[2 * 256 * 64];
  __shared__ bf16 Bs[2 * 256 * 64];
  constexpr int BUFB = 256 * 64 * 2;  // bytes per buffer

  const int tid = threadIdx.x;
  const int wave = tid >> 6;
  const int lane = tid & 63;
  const int l16 = lane & 15;
  const int quad = lane >> 4;
  const int wm = wave >> 2;   // 0..1 -> rows wm*128..+127
  const int wn = wave & 3;    // 0..3 -> cols wn*64..+63

  // XCD-aware bijective swizzle (both launches have nwg % 8 == 0)
  int id = blockIdx.y * gridDim.x + blockIdx.x;
  const int nwg = gridDim.x * gridDim.y;
  const int chunk = nwg >> 3;
  id = (id & 7) * chunk + (id >> 3);
  const int bx = id % gridDim.x;
  const int by = id / gridDim.x;
  const int m0 = by * 256;
  const int n0 = bx * 256;

  const int NT = K >> 6;           // K-tiles of 64 (always even here: 40 / 32)
  const int xorv = (l16 & 7) << 4; // T2 swizzle key for fragment reads

  // staging source bases (per-lane, pre-swizzled: col chunk = (l&7)^(l>>3))
  const bf16* srcA = A + (size_t)(m0 + wave * 16 + (lane >> 3)) * K + ((lane & 7) ^ (lane >> 3)) * 8;
  const bf16* srcB = Bt + (size_t)(n0 + wave * 16 + (lane >> 3)) * K + ((lane & 7) ^ (lane >> 3)) * 8;

  auto stage_a = [&](int buf, int h, int kt) {
    const bf16* sp = srcA + (size_t)(h * 128) * K + kt * 64;
    char* dp = (char*)As + buf * BUFB + h * 16384 + wave * 2048;  // wave-uniform; HW adds lane*16
    GLOAD_LDS(sp, dp);
    GLOAD_LDS(sp + (size_t)8 * K, dp + 1024);
  };
  auto stage_b = [&](int buf, int h, int kt) {
    const bf16* sp = srcB + (size_t)(h * 128) * K + kt * 64;
    char* dp = (char*)Bs + buf * BUFB + h * 16384 + wave * 2048;
    GLOAD_LDS(sp, dp);
    GLOAD_LDS(sp + (size_t)8 * K, dp + 1024);
  };

  bf16x8 afr[8][2];  // a_lo = afr[0..3], a_hi = afr[4..7]; x k-slice 0..1
  bf16x8 bfr[4][2];  // b_lo = bfr[0..1], b_hi = bfr[2..3]
  f32x4 acc[8][4] = {};

  auto read_a = [&](const char* Ab, int I0) {
#pragma unroll
    for (int ii = 0; ii < 4; ++ii)
#pragma unroll
      for (int s = 0; s < 2; ++s)
        afr[I0 + ii][s] = *(const bf16x8*)(
            Ab + (wm * 128 + (I0 + ii) * 16 + l16) * 128 + ((s * 64 + quad * 16) ^ xorv));
  };
  auto read_b = [&](const char* Bb, int J0) {
#pragma unroll
    for (int jj = 0; jj < 2; ++jj)
#pragma unroll
      for (int s = 0; s < 2; ++s)
        bfr[J0 + jj][s] = *(const bf16x8*)(
            Bb + (wn * 64 + (J0 + jj) * 16 + l16) * 128 + ((s * 64 + quad * 16) ^ xorv));
  };
  auto mq = [&](int I0, int J0) {
#pragma unroll
    for (int ii = 0; ii < 4; ++ii)
#pragma unroll
      for (int jj = 0; jj < 2; ++jj)
#pragma unroll
        for (int s = 0; s < 2; ++s)
          acc[I0 + ii][J0 + jj] = __builtin_amdgcn_mfma_f32_16x16x32_bf16(
              afr[I0 + ii][s], bfr[J0 + jj][s], acc[I0 + ii][J0 + jj], 0, 0, 0);
  };

  const char* A0 = (const char*)As;
  const char* B0 = (const char*)Bs;
  const char* A1 = (const char*)As + BUFB;
  const char* B1 = (const char*)Bs + BUFB;

  // prologue: t0 full -> buf0 (8 loads), t1 A-halves -> buf1 (4 loads)
  stage_a(0, 0, 0); stage_a(0, 1, 0);
  stage_b(0, 0, 0); stage_b(0, 1, 0);
  stage_a(1, 0, 1); stage_a(1, 1, 1);
  asm volatile("s_waitcnt vmcnt(4)" ::: "memory");  // own-wave t0 landed
  __builtin_amdgcn_s_barrier();                     // cross-wave visibility
  read_a(A0, 0);   // a_lo(0)
  read_b(B0, 0);   // b_lo(0)
  read_b(B0, 2);   // b_hi(0)

  // one tile = 4 phases; all reads are 1-2 phases ahead of their MFMA use
  auto tile = [&](int T, const char* Ac, const char* Bc,
                  const char* An, const char* Bn, int bufc, int bufn) {
    // ---- P1: pre-read a_hi(T); stage Bh0(T+1); MFMA a_lo x b_lo
    read_a(Ac, 4);
    if (T + 1 < NT) stage_b(bufn, 0, T + 1);
    __builtin_amdgcn_s_barrier();
    __builtin_amdgcn_s_setprio(1);
    mq(0, 0);
    __builtin_amdgcn_s_setprio(0);
    __builtin_amdgcn_s_barrier();
    // ---- P2: stage Bh1(T+1); vmcnt(4) drains Ah(T+1) before barrier; MFMA a_lo x b_hi
    if (T + 1 < NT) stage_b(bufn, 1, T + 1);
    asm volatile("s_waitcnt vmcnt(4)" ::: "memory");
    __builtin_amdgcn_s_barrier();
    __builtin_amdgcn_s_setprio(1);
    mq(0, 2);
    __builtin_amdgcn_s_setprio(0);
    __builtin_amdgcn_s_barrier();
    // ---- P3: pre-read a_lo(T+1) (Ah(T+1) guaranteed by P2 vmcnt+bar);
    //          lgkm(8) = a_hi(T) reads done -> bufc.A free; stage Ah0(T+2);
    //          vmcnt(2) drains Bh0/Bh1(T+1) before barrier; MFMA a_hi x b_hi
    if (T + 1 < NT) read_a(An, 0);
    asm volatile("s_waitcnt lgkmcnt(8)" ::: "memory");
    if (T + 2 < NT) stage_a(bufc, 0, T + 2);
    asm volatile("s_waitcnt vmcnt(2)" ::: "memory");
    __builtin_amdgcn_s_barrier();
    __builtin_amdgcn_s_setprio(1);
    mq(4, 2);
    __builtin_amdgcn_s_setprio(0);
    __builtin_amdgcn_s_barrier();
    // ---- P4: pre-read b_hi(T+1) (landed per P3 vmcnt+bar); stage Ah1(T+2);
    //          MFMA a_hi x b_lo; post-read b_lo(T+1)
    if (T + 1 < NT) read_b(Bn, 2);
    if (T + 2 < NT) stage_a(bufc, 1, T + 2);
    __builtin_amdgcn_s_barrier();
    __builtin_amdgcn_s_setprio(1);
    mq(4, 0);
    __builtin_amdgcn_s_setprio(0);
    if (T + 1 < NT) read_b(Bn, 0);
    __builtin_amdgcn_s_barrier();
  };

  for (int t = 0; t < NT; t += 2) {
    tile(t,     A0, B0, A1, B1, 0, 1);
    tile(t + 1, A1, B1, A0, B0, 1, 0);
  }

  // epilogue: C/D layout col = lane&15, row = quad*4 + reg
#pragma unroll
  for (int i = 0; i < 8; ++i)
#pragma unroll
    for (int j = 0; j < 4; ++j) {
      const int col = n0 + wn * 64 + j * 16 + l16;
#pragma unroll
      for (int r = 0; r < 4; ++r) {
        const int row = m0 + wm * 128 + i * 16 + quad * 4 + r;
        if constexpr (__is_same(OutT, float))
          C[(size_t)row * N + col] = acc[i][j][r];
        else
          C[(size_t)row * N + col] = __float2bfloat16(acc[i][j][r]);
      }
    }
}

// ---------- fused mid: RMSNorm+RoPE (q,k) + V transpose (1 launch) ----------
__global__ __launch_bounds__(256) void k_mid(
    const bf16* __restrict__ qkv, const int* __restrict__ positions,
    const float* __restrict__ qw, const float* __restrict__ kw,
    bf16* __restrict__ q_r, bf16* __restrict__ k_r, bf16* __restrict__ v_t)
{
  __shared__ bf16 t[64 * 72];
  const int tid = threadIdx.x;
  const int b = blockIdx.x;
  if (b < 12288) {
    const int tpos = b & 4095;
    const int slot = (b >> 12) * 4 + (tid >> 6);
    const int lane = tid & 63;
    const bf16* base = qkv + (size_t)tpos * 4096 + slot * 256;
    float x[4];
#pragma unroll
    for (int i = 0; i < 4; ++i) x[i] = __bfloat162float(base[lane + 64 * i]);
    float ss = x[0] * x[0] + x[1] * x[1] + x[2] * x[2] + x[3] * x[3];
#pragma unroll
    for (int off = 1; off < 64; off <<= 1) ss += __shfl_xor(ss, off, 64);
    const float rn = rsqrtf(ss * (1.0f / 256.0f) + 1e-6f);
    const float* w = (slot < 8) ? qw : kw;
    float nv[4];
#pragma unroll
    for (int i = 0; i < 4; ++i)
      nv[i] = x[i] * rn * (1.0f + w[lane + 64 * i]);
    const float p = (float)positions[tpos];
    const float C_LOG2_10K_128 = 13.287712379549449f / 128.0f;
    const float f0 = p * exp2f(-(float)lane * C_LOG2_10K_128);
    const float f1 = p * exp2f(-(float)(lane + 64) * C_LOG2_10K_128);
    const float c0 = cosf(f0), s0 = sinf(f0);
    const float c1 = cosf(f1), s1 = sinf(f1);
    const float o0 = nv[0] * c0 - nv[2] * s0;
    const float o2 = nv[2] * c0 + nv[0] * s0;
    const float o1 = nv[1] * c1 - nv[3] * s1;
    const float o3 = nv[3] * c1 + nv[1] * s1;
    bf16* dst = (slot < 8) ? (q_r + ((size_t)slot * T_SEQ + tpos) * 256)
                           : (k_r + ((size_t)(slot - 8) * T_SEQ + tpos) * 256);
    dst[lane]       = __float2bfloat16(o0);
    dst[lane + 64]  = __float2bfloat16(o1);
    dst[lane + 128] = __float2bfloat16(o2);
    dst[lane + 192] = __float2bfloat16(o3);
    return;
  }
  const int b2 = b - 12288;
  const int c0 = (b2 & 3) * 64;          // col within [0,256) head-dim slice
  const int r0 = ((b2 >> 2) & 63) * 64;  // row (token)
  const int z = b2 >> 8;                 // kv head
  const bf16* src = qkv + 3072 + (size_t)z * 256;
  bf16* dst = v_t + (size_t)z * 256 * 4096;
  const int rr = tid >> 3;
  const int cc = (tid & 7) * 8;
#pragma unroll
  for (int p = 0; p < 2; ++p) {
    bf16x8 v = *(const bf16x8*)(src + (size_t)(r0 + p * 32 + rr) * 4096 + c0 + cc);
    *(bf16x8*)(&t[(p * 32 + rr) * 72 + cc]) = v;
  }
  __syncthreads();
#pragma unroll
  for (int p = 0; p < 2; ++p) {
    const int n = p * 32 + rr;
    bf16x8 v;
#pragma unroll
    for (int i = 0; i < 8; ++i) v[i] = ((const __bf16*)t)[(cc + i) * 72 + n];
    *(bf16x8*)(dst + (size_t)(c0 + n) * 4096 + r0 + cc) = v;
  }
}

// ---------- flash attention, sliding window, GQA (unchanged) ----------
__global__ __launch_bounds__(256, 2) void k_attn(
    const bf16* __restrict__ q_r, const bf16* __restrict__ k_r,
    const bf16* __restrict__ vt, bf16* __restrict__ attn)
{
  __shared__ bf16 Ks[64 * 256];    // 32KB [key][d], d-chunk xor (key&7)
  __shared__ bf16 Vts[256 * 64];   // 32KB [d][key], key-chunk xor (d&7)
  __shared__ bf16 Ps[4 * 16 * 64]; // 8KB per-wave P: [16 q][64 k], chunk xor (row&7)
  const int tid = threadIdx.x;
  const int w = tid >> 6;
  const int lane = tid & 63;
  const int l16 = lane & 15;
  const int quad = lane >> 4;
  const int k7 = l16 & 7;
  const int bid = blockIdx.y * gridDim.x + blockIdx.x;   // 512 blocks
  const int orig = (bid & 7) * 64 + (bid >> 3);
  const int q0 = (orig & 63) * 64;
  const int h = orig >> 6;
  const int kh = h >> 1;
  const int qw0 = q0 + w * 16;   // this wave's 16 q-rows

  bf16x8 qf[8];
  {
    const bf16* qb = q_r + ((size_t)h * T_SEQ + qw0 + l16) * HD + quad * 8;
#pragma unroll
    for (int s = 0; s < 8; ++s) qf[s] = *(const bf16x8*)(qb + s * 32);
  }
  f32x4 O[16] = {};
  float mrow[4], lrow[4];
#pragma unroll
  for (int r = 0; r < 4; ++r) { mrow[r] = -1e30f; lrow[r] = 0.f; }

  const int rK = tid >> 5;
  const int rV = tid >> 3;
  const bf16* kgb = k_r + ((size_t)kh * T_SEQ + rK) * HD + (((tid & 31) ^ rK) * 8);
  const bf16* vgb = vt + ((size_t)kh * HD + rV) * T_SEQ + (((tid & 7) ^ (rV & 7)) * 8);

  auto stage_K = [&](int j) {
    char* kl = (char*)Ks + w * 1024;
#pragma unroll
    for (int p = 0; p < 8; ++p)
      GLOAD_LDS(kgb + (size_t)(j + p * 8) * HD, kl + p * 4096);
  };
  auto stage_V = [&](int j) {
    char* vl = (char*)Vts + w * 1024;
#pragma unroll
    for (int p = 0; p < 8; ++p)
      GLOAD_LDS(vgb + (size_t)p * 32 * T_SEQ + j, vl + p * 4096);
  };

  const int jstart = (q0 >= 1024) ? (q0 - 1024) : 0;
  bf16* Pw = Ps + w * 1024;

  stage_K(jstart);
  stage_V(jstart);
  for (int j0 = jstart; j0 <= q0; j0 += 64) {
    asm volatile("s_waitcnt vmcnt(8)" ::: "memory");  // K(t) landed (V may be in flight)
    __builtin_amdgcn_s_barrier();

    f32x4 sa[4] = {};
#pragma unroll
    for (int s = 0; s < 8; ++s) {
      bf16x8 kf0 = *(const bf16x8*)((const char*)Ks + (0 * 16 + l16) * 512 + (((s * 4 + quad) ^ k7) * 16));
      bf16x8 kf1 = *(const bf16x8*)((const char*)Ks + (1 * 16 + l16) * 512 + (((s * 4 + quad) ^ k7) * 16));
      bf16x8 kf2 = *(const bf16x8*)((const char*)Ks + (2 * 16 + l16) * 512 + (((s * 4 + quad) ^ k7) * 16));
      bf16x8 kf3 = *(const bf16x8*)((const char*)Ks + (3 * 16 + l16) * 512 + (((s * 4 + quad) ^ k7) * 16));
      sa[0] = __builtin_amdgcn_mfma_f32_16x16x32_bf16(qf[s], kf0, sa[0], 0, 0, 0);
      sa[1] = __builtin_amdgcn_mfma_f32_16x16x32_bf16(qf[s], kf1, sa[1], 0, 0, 0);
      sa[2] = __builtin_amdgcn_mfma_f32_16x16x32_bf16(qf[s], kf2, sa[2], 0, 0, 0);
      sa[3] = __builtin_amdgcn_mfma_f32_16x16x32_bf16(qf[s], kf3, sa[3], 0, 0, 0);
    }

    const bool interior = (j0 + 63 <= qw0) && (qw0 + 15 - j0 < WINDOW);
    float sm[4][4];
    if (interior) {
#pragma unroll
      for (int kb = 0; kb < 4; ++kb)
#pragma unroll
        for (int r = 0; r < 4; ++r) sm[kb][r] = sa[kb][r] * SM_SCALE;
    } else {
#pragma unroll
      for (int kb = 0; kb < 4; ++kb)
#pragma unroll
        for (int r = 0; r < 4; ++r) {
          const int i = qw0 + quad * 4 + r;
          const int j = j0 + kb * 16 + l16;
          sm[kb][r] = ((j <= i) && (i - j < WINDOW)) ? sa[kb][r] * SM_SCALE : -1e30f;
        }
    }
    float mx[4];
    bool ok = true;
#pragma unroll
    for (int r = 0; r < 4; ++r) {
      float m2 = fmaxf(fmaxf(sm[0][r], sm[1][r]), fmaxf(sm[2][r], sm[3][r]));
#pragma unroll
      for (int off = 1; off < 16; off <<= 1) m2 = fmaxf(m2, __shfl_xor(m2, off, 64));
      mx[r] = m2;
      ok = ok && (m2 <= mrow[r] + 8.0f);
    }
    if (!__all(ok)) {  // T13 defer-max
#pragma unroll
      for (int r = 0; r < 4; ++r) {
        const float mnew = fmaxf(mrow[r], mx[r]);
        const float alpha = __expf(mrow[r] - mnew);
        lrow[r] *= alpha;
#pragma unroll
        for (int n = 0; n < 16; ++n) O[n][r] *= alpha;
        mrow[r] = mnew;
      }
    }
#pragma unroll
    for (int r = 0; r < 4; ++r) {
      const int prow = quad * 4 + r;
      float rs = 0.f;
#pragma unroll
      for (int kb = 0; kb < 4; ++kb) {
        const float p = __expf(sm[kb][r] - mrow[r]);
        rs += p;
        Pw[prow * 64 + (((kb * 2 + (l16 >> 3)) ^ (prow & 7)) * 8) + (l16 & 7)] = __float2bfloat16(p);
      }
#pragma unroll
      for (int off = 1; off < 16; off <<= 1) rs += __shfl_xor(rs, off, 64);
      lrow[r] += rs;
    }

    asm volatile("s_waitcnt vmcnt(0)" ::: "memory");  // V(t) landed (hidden under QK+sm)
    __builtin_amdgcn_s_barrier();
    if (j0 < q0) stage_K(j0 + 64);

    asm volatile("s_waitcnt lgkmcnt(0)" ::: "memory");
    __builtin_amdgcn_sched_barrier(0);
    const bf16x8 pf0 = *(const bf16x8*)(Pw + l16 * 64 + ((quad ^ k7) * 8));
    const bf16x8 pf1 = *(const bf16x8*)(Pw + l16 * 64 + (((4 + quad) ^ k7) * 8));
#pragma unroll
    for (int n = 0; n < 16; ++n) {
      const bf16x8 vf0 = *(const bf16x8*)((const char*)Vts + (n * 16 + l16) * 128 + ((quad ^ k7) * 16));
      const bf16x8 vf1 = *(const bf16x8*)((const char*)Vts + (n * 16 + l16) * 128 + (((4 + quad) ^ k7) * 16));
      O[n] = __builtin_amdgcn_mfma_f32_16x16x32_bf16(pf0, vf0, O[n], 0, 0, 0);
      O[n] = __builtin_amdgcn_mfma_f32_16x16x32_bf16(pf1, vf1, O[n], 0, 0, 0);
    }
    __builtin_amdgcn_s_barrier();
    if (j0 < q0) stage_V(j0 + 64);
  }
#pragma unroll
  for (int r = 0; r < 4; ++r) {
    const float inv = 1.0f / lrow[r];
    const size_t row = qw0 + quad * 4 + r;
#pragma unroll
    for (int n = 0; n < 16; ++n)
      attn[row * (NH * HD) + h * HD + n * 16 + l16] = __float2bfloat16(O[n][r] * inv);
  }
}

extern "C" void kernel_launch(void* const* d_in, const int* in_sizes, int n_in,
                              void* d_out, int out_size, void* d_ws, size_t ws_size,
                              hipStream_t stream)
{
  const float* x  = (const float*)d_in[0];
  const int* pos  = (const int*)d_in[1];
  const float* Wq = (const float*)d_in[2];
  const float* Wk = (const float*)d_in[3];
  const float* Wv = (const float*)d_in[4];
  const float* Wo = (const float*)d_in[5];
  const float* qw = (const float*)d_in[6];
  const float* kw = (const float*)d_in[7];
  float* out = (float*)d_out;   // reference output dtype is FP32

  char* ws = (char*)d_ws;
  size_t off = 0;
  bf16* Wqkv_t = (bf16*)(ws + off); off += (size_t)4096 * 2560 * 2;  // dead after GEMM1; reused as attn_b
  bf16* Wo_t   = (bf16*)(ws + off); off += (size_t)2560 * 2048 * 2;
  bf16* qkv_b  = (bf16*)(ws + off); off += (size_t)4096 * 4096 * 2;
  bf16* q_r    = (bf16*)(ws + off); off += (size_t)8 * 4096 * 256 * 2;
  bf16* k_r    = (bf16*)(ws + off); off += (size_t)4 * 4096 * 256 * 2;
  bf16* v_t    = (bf16*)(ws + off); off += (size_t)4 * 256 * 4096 * 2;
  bf16* attn_b = Wqkv_t;
  bf16* x_b = q_r;
  if (ws_size < off) return;  // insufficient workspace -> fail loudly

  // fused prep: x f2b (5120 blocks) + 4 weight transposes (3840 tiles), 1 launch
  k_prep<<<dim3(8960), 256, 0, stream>>>(x, Wq, Wk, Wv, Wo, x_b, Wqkv_t, Wo_t);
  // fused QKV projection: [4096,2560] x [2560,4096] -> [4096,4096] (bf16 out), 256 blocks
  k_gemm8<bf16><<<dim3(16, 16), 512, 0, stream>>>(x_b, Wqkv_t, qkv_b, 4096, 4096, 2560);
  // fused mid: RMSNorm+RoPE (12288 blocks) + V transpose (1024 tiles), 1 launch
  k_mid<<<dim3(13312), 256, 0, stream>>>(qkv_b, pos, qw, kw, q_r, k_r, v_t);
  // flash attention: 512 blocks x 256 threads (4 waves, 16 q-rows each, KVBLK=64)
  k_attn<<<dim3(64, 8), 256, 0, stream>>>(q_r, k_r, v_t, attn_b);
  // output projection: [4096,2048] x [2048,2560] -> out (FP32 out), 160 blocks
  k_gemm8<float><<<dim3(10, 16), 512, 0, stream>>>(attn_b, Wo_t, out, 4096, 2560, 2048);
}